// Round 3
// baseline (1089.329 us; speedup 1.0000x reference)
//
#include <hip/hip_runtime.h>
#include <hip/hip_bf16.h>
#include <math.h>

#define NN 100000
#define EE 800000

static constexpr int SCAN_CH = 512;
static constexpr int NCH = (NN + SCAN_CH - 1) / SCAN_CH; // 196

__device__ __forceinline__ float leaky(float a) { return a >= 0.0f ? a : 0.2f * a; }
__device__ __forceinline__ float quantize(float v, float s) {
    float r = rintf(v / s);
    r = fminf(fmaxf(r, -128.0f), 127.0f);
    return r * s;
}

// ---------------- init: zero counters ----------------
__global__ void k_init(unsigned* deg_src, unsigned* deg_dst, unsigned* s1, unsigned* s2) {
    int i = blockIdx.x * 256 + threadIdx.x;
    if (i < NN) { deg_src[i] = 0; deg_dst[i] = 0; }
    if (i < 256) { s1[i] = 0; s2[i] = 0; }
}

// ---------------- degree count ----------------
__global__ void k_deg(const int* ei, unsigned* deg_src, unsigned* deg_dst) {
    int e = blockIdx.x * 256 + threadIdx.x;
    if (e < EE) {
        atomicAdd(&deg_src[ei[e]], 1u);
        atomicAdd(&deg_dst[ei[EE + e]], 1u);
    }
}

// ---------------- scan (3 kernels) ----------------
__global__ void k_scan_chunksum(const unsigned* deg_dst, unsigned* chunkSum) {
    __shared__ unsigned red[256];
    int b = blockIdx.x, t = threadIdx.x;
    int g0 = b * SCAN_CH + t;
    unsigned v = 0;
    if (g0 < NN) v += deg_dst[g0];
    if (g0 + 256 < NN && t + 256 < SCAN_CH) v += deg_dst[g0 + 256];
    red[t] = v; __syncthreads();
    for (int s = 128; s > 0; s >>= 1) { if (t < s) red[t] += red[t + s]; __syncthreads(); }
    if (t == 0) chunkSum[b] = red[0];
}

__global__ void k_scan_chunkoff(const unsigned* chunkSum, unsigned* chunkOff, unsigned* off) {
    __shared__ unsigned sc[256];
    int t = threadIdx.x;
    unsigned v = (t < NCH) ? chunkSum[t] : 0u;
    sc[t] = v; __syncthreads();
    for (int d = 1; d < 256; d <<= 1) {
        unsigned add = (t >= d) ? sc[t - d] : 0u; __syncthreads();
        sc[t] += add; __syncthreads();
    }
    if (t < NCH) chunkOff[t] = sc[t] - v;
    if (t == 255) off[NN] = sc[255];
}

// final scan + cursor init + degree-norm tables (fused)
__global__ void k_scan_final(const unsigned* deg_dst, const unsigned* chunkOff,
                             unsigned* off, unsigned* cursor,
                             const unsigned* deg_src, const float* a1p, const float* a2p,
                             float* rn1, float* rn2) {
    __shared__ unsigned sc[256];
    int b = blockIdx.x, t = threadIdx.x;
    int g0 = b * SCAN_CH + 2 * t;
    unsigned a = (g0 < NN) ? deg_dst[g0] : 0u;
    unsigned c = (g0 + 1 < NN) ? deg_dst[g0 + 1] : 0u;
    unsigned ps = a + c;
    sc[t] = ps; __syncthreads();
    for (int d = 1; d < 256; d <<= 1) {
        unsigned add = (t >= d) ? sc[t - d] : 0u; __syncthreads();
        sc[t] += add; __syncthreads();
    }
    unsigned base = chunkOff[b] + sc[t] - ps;
    float e1 = -a1p[0], e2 = -a2p[0];
    if (g0 < NN) {
        off[g0] = base; cursor[g0] = base;
        float d0 = (float)deg_src[g0] + 1.0f;
        rn1[g0] = powf(d0, e1); rn2[g0] = powf(d0, e2);
    }
    if (g0 + 1 < NN) {
        off[g0 + 1] = base + a; cursor[g0 + 1] = base + a;
        float d1 = (float)deg_src[g0 + 1] + 1.0f;
        rn1[g0 + 1] = powf(d1, e1); rn2[g0 + 1] = powf(d1, e2);
    }
}

// ---------------- scatter: sort edges by dst ----------------
__global__ void k_scatter(const int* ei, unsigned* cursor, unsigned* pos_of_edge,
                          unsigned* src_sorted) {
    int e = blockIdx.x * 256 + threadIdx.x;
    if (e < EE) {
        int d = ei[EE + e];
        unsigned pos = atomicAdd(&cursor[d], 1u);
        pos_of_edge[e] = pos;
        src_sorted[pos] = (unsigned)ei[e];
    }
}

// ---------------- weight fake-quant + a_edge projection vectors ----------------
// block 0: layer 1, block 1: layer 2
__global__ void k_weights(const float* W1, const float* W2,
                          const float* We1, const float* ae1,
                          const float* We2, const float* ae2,
                          float* Wq1, float* Wq2, float* v1, float* v2) {
    __shared__ float red[256];
    int t = threadIdx.x;
    const float* W  = blockIdx.x ? W2 : W1;
    const float* We = blockIdx.x ? We2 : We1;
    const float* ae = blockIdx.x ? ae2 : ae1;
    float* Wq = blockIdx.x ? Wq2 : Wq1;
    float* v  = blockIdx.x ? v2 : v1;
    float m = 0.0f;
    for (int i = t; i < 8192; i += 256) m = fmaxf(m, fabsf(W[i]));
    red[t] = m; __syncthreads();
    for (int s = 128; s > 0; s >>= 1) { if (t < s) red[t] = fmaxf(red[t], red[t + s]); __syncthreads(); }
    float s1 = fmaxf(red[0], 1e-8f) / 127.0f;
    __syncthreads();
    for (int i = t; i < 8192; i += 256) Wq[i] = quantize(W[i], s1);
    if (t < 64) {
        int h = t >> 5, d = t & 31;
        float acc = 0.0f;
        for (int c = 0; c < 64; ++c) acc += We[(h * 64 + c) * 32 + d] * ae[h * 64 + c];
        v[t] = acc;
    }
}

// ---------------- a_edge for both layers, written in dst-sorted order ----------------
__global__ void k_aedge(const float* edge_attr, const float* v1, const float* v2,
                        const unsigned* pos_of_edge, float2* ae1s, float2* ae2s) {
    __shared__ float vs[128];
    int t = threadIdx.x;
    if (t < 64) vs[t] = v1[t];
    else if (t < 128) vs[t] = v2[t - 64];
    __syncthreads();
    int e = blockIdx.x * 256 + t;
    if (e >= EE) return;
    const float4* ea = (const float4*)(edge_attr + (size_t)e * 32);
    float a00 = 0, a01 = 0, a10 = 0, a11 = 0;
#pragma unroll
    for (int q = 0; q < 8; ++q) {
        float4 w = ea[q];
        float xs4[4] = {w.x, w.y, w.z, w.w};
#pragma unroll
        for (int j = 0; j < 4; ++j) {
            int d = q * 4 + j;
            a00 += xs4[j] * vs[d];
            a01 += xs4[j] * vs[32 + d];
            a10 += xs4[j] * vs[64 + d];
            a11 += xs4[j] * vs[96 + d];
        }
    }
    unsigned pos = pos_of_edge[e];
    ae1s[pos] = make_float2(a00, a01);
    ae2s[pos] = make_float2(a10, a11);
}

// ---------------- h = xn @ Wq.T (+ a_src/a_dst dots) ----------------
// Each lane computes BOTH heads for feature l (weight rows l and 64+l in VGPRs),
// writes interleaved float2 -> aggregate gathers one contiguous 512B row.
__global__ void k_hproj(const float* __restrict__ in, const float* __restrict__ rn,
                        const float* __restrict__ Wq,
                        const float* __restrict__ att_s, const float* __restrict__ att_d,
                        float2* __restrict__ hp, float2* __restrict__ asrcv,
                        float2* __restrict__ adstv) {
    __shared__ float xs[32][64];   // 8 KB
    int t = threadIdx.x;
    int node0 = blockIdx.x * 32;
    for (int i = t; i < 512; i += 256) {
        int n = i >> 4, c4 = i & 15;
        int node = node0 + n;
        float4 v = make_float4(0.f, 0.f, 0.f, 0.f);
        if (node < NN) {
            v = ((const float4*)(in + (size_t)node * 64))[c4];
            if (rn) { float r = rn[node]; v.x *= r; v.y *= r; v.z *= r; v.w *= r; }
        }
        ((float4*)xs[n])[c4] = v;
    }
    int w = t >> 6, l = t & 63;
    float4 w0[16], w1[16];
    const float4* wp0 = (const float4*)(Wq + (size_t)l * 64);
    const float4* wp1 = (const float4*)(Wq + (size_t)(64 + l) * 64);
#pragma unroll
    for (int q = 0; q < 16; ++q) { w0[q] = wp0[q]; w1[q] = wp1[q]; }
    float as0 = att_s[l], as1 = att_s[64 + l];
    float ad0 = att_d[l], ad1 = att_d[64 + l];
    __syncthreads();
    for (int nn = 0; nn < 8; ++nn) {
        int node = node0 + w * 8 + nn;
        if (node >= NN) break;
        const float4* xr = (const float4*)xs[w * 8 + nn];
        float a0 = 0.0f, a1 = 0.0f;
#pragma unroll
        for (int q = 0; q < 16; ++q) {
            float4 xv = xr[q];             // uniform address -> LDS broadcast
            a0 += xv.x * w0[q].x + xv.y * w0[q].y + xv.z * w0[q].z + xv.w * w0[q].w;
            a1 += xv.x * w1[q].x + xv.y * w1[q].y + xv.z * w1[q].z + xv.w * w1[q].w;
        }
        hp[(size_t)node * 64 + l] = make_float2(a0, a1);
        float ps0 = a0 * as0, ps1 = a1 * as1, pd0 = a0 * ad0, pd1 = a1 * ad1;
#pragma unroll
        for (int m = 32; m > 0; m >>= 1) {
            ps0 += __shfl_xor(ps0, m, 64);
            ps1 += __shfl_xor(ps1, m, 64);
            pd0 += __shfl_xor(pd0, m, 64);
            pd1 += __shfl_xor(pd1, m, 64);
        }
        if (l == 0) {
            asrcv[node] = make_float2(ps0, ps1);
            adstv[node] = make_float2(pd0, pd1);
        }
    }
}

// ---------------- fused softmax+aggregate: wave per dst node, 4-way unrolled ----------------
__global__ void k_aggregate(const unsigned* __restrict__ off, const unsigned* __restrict__ src_s,
                            const float2* __restrict__ aes,
                            const float2* __restrict__ asrcv, const float2* __restrict__ adstv,
                            const float2* __restrict__ hp, const float* __restrict__ bias,
                            float* __restrict__ outp, unsigned* __restrict__ amax_slots) {
    int t = threadIdx.x;
    int l = t & 63;
    int node = blockIdx.x * 4 + (t >> 6);
    if (node >= NN) return;
    unsigned s0 = off[node], e0 = off[node + 1];
    float2 adv = adstv[node];
    float acc0 = 0.f, acc1 = 0.f, sum0 = 0.f, sum1 = 0.f;
    unsigned i = s0;
    for (; i + 4 <= e0; i += 4) {
        unsigned sa = src_s[i], sb = src_s[i + 1], sc = src_s[i + 2], sd = src_s[i + 3];
        float2 ea = aes[i], eb = aes[i + 1], ec = aes[i + 2], ed = aes[i + 3];
        float2 aa = asrcv[sa], ab = asrcv[sb], ac = asrcv[sc], ad = asrcv[sd];
        float2 ha = hp[(size_t)sa * 64 + l];
        float2 hb = hp[(size_t)sb * 64 + l];
        float2 hc = hp[(size_t)sc * 64 + l];
        float2 hd = hp[(size_t)sd * 64 + l];
        float pa0 = __expf(leaky(aa.x + adv.x + ea.x));
        float pa1 = __expf(leaky(aa.y + adv.y + ea.y));
        float pb0 = __expf(leaky(ab.x + adv.x + eb.x));
        float pb1 = __expf(leaky(ab.y + adv.y + eb.y));
        float pc0 = __expf(leaky(ac.x + adv.x + ec.x));
        float pc1 = __expf(leaky(ac.y + adv.y + ec.y));
        float pd0 = __expf(leaky(ad.x + adv.x + ed.x));
        float pd1 = __expf(leaky(ad.y + adv.y + ed.y));
        sum0 += pa0 + pb0 + pc0 + pd0;
        sum1 += pa1 + pb1 + pc1 + pd1;
        acc0 = fmaf(pa0, ha.x, fmaf(pb0, hb.x, fmaf(pc0, hc.x, fmaf(pd0, hd.x, acc0))));
        acc1 = fmaf(pa1, ha.y, fmaf(pb1, hb.y, fmaf(pc1, hc.y, fmaf(pd1, hd.y, acc1))));
    }
    for (; i < e0; ++i) {
        unsigned s = src_s[i];
        float2 ev = aes[i];
        float2 av = asrcv[s];
        float2 hv = hp[(size_t)s * 64 + l];
        float p0 = __expf(leaky(av.x + adv.x + ev.x));
        float p1 = __expf(leaky(av.y + adv.y + ev.y));
        sum0 += p0; sum1 += p1;
        acc0 = fmaf(p0, hv.x, acc0);
        acc1 = fmaf(p1, hv.y, acc1);
    }
    float o = 0.5f * (acc0 / (sum0 + 1e-16f) + acc1 / (sum1 + 1e-16f)) + bias[l];
    outp[(size_t)node * 64 + l] = o;
    float v = fabsf(o);
#pragma unroll
    for (int m = 32; m > 0; m >>= 1) v = fmaxf(v, __shfl_xor(v, m, 64));
    if (l == 0) atomicMax(&amax_slots[node & 255], __float_as_uint(v));
}

// ---------------- reduce 256 absmax slots -> scale ----------------
__global__ void k_amax_reduce(const unsigned* slots, float* s_out) {
    __shared__ unsigned red[256];
    int t = threadIdx.x;
    red[t] = slots[t]; __syncthreads();
    for (int s = 128; s > 0; s >>= 1) {
        if (t < s) red[t] = (red[t] > red[t + s]) ? red[t] : red[t + s];
        __syncthreads();
    }
    if (t == 0) s_out[0] = fmaxf(__uint_as_float(red[0]), 1e-8f) / 127.0f;
}

// ---------------- quant + relu + degree-norm (layer1 -> layer2 input) ----------------
__global__ void k_quant_relu_norm(float* buf, const float* s_in, const float* rn2) {
    int i = blockIdx.x * 256 + threadIdx.x;
    if (i >= NN * 64) return;
    float s = s_in[0];
    float q = quantize(buf[i], s);
    buf[i] = fmaxf(q, 0.0f) * rn2[i >> 6];
}

// ---------------- final output fake-quant in place ----------------
__global__ void k_quant_out(float* buf, const float* s_in) {
    int i = blockIdx.x * 256 + threadIdx.x;
    if (i >= NN * 64) return;
    buf[i] = quantize(buf[i], s_in[0]);
}

extern "C" void kernel_launch(void* const* d_in, const int* in_sizes, int n_in,
                              void* d_out, int out_size, void* d_ws, size_t ws_size,
                              hipStream_t stream) {
    const float* x     = (const float*)d_in[0];
    const int*   ei    = (const int*)d_in[1];
    const float* eattr = (const float*)d_in[2];
    const float* a1    = (const float*)d_in[3];
    const float* W1    = (const float*)d_in[4];
    const float* We1   = (const float*)d_in[5];
    const float* as1   = (const float*)d_in[6];
    const float* ad1   = (const float*)d_in[7];
    const float* ae1   = (const float*)d_in[8];
    const float* b1    = (const float*)d_in[9];
    const float* a2    = (const float*)d_in[10];
    const float* W2    = (const float*)d_in[11];
    const float* We2   = (const float*)d_in[12];
    const float* as2   = (const float*)d_in[13];
    const float* ad2   = (const float*)d_in[14];
    const float* ae2   = (const float*)d_in[15];
    const float* b2    = (const float*)d_in[16];
    float* out = (float*)d_out;

    char* w = (char*)d_ws;
    size_t o = 0;
    auto alloc = [&](size_t bytes) -> char* {
        char* p = w + o;
        o += (bytes + 255) & ~(size_t)255;
        return p;
    };
    unsigned* deg_src  = (unsigned*)alloc((size_t)NN * 4);
    unsigned* deg_dst  = (unsigned*)alloc((size_t)NN * 4);
    unsigned* offs     = (unsigned*)alloc((size_t)(NN + 1) * 4);
    unsigned* cursor   = (unsigned*)alloc((size_t)NN * 4);
    unsigned* chunkSum = (unsigned*)alloc((size_t)NCH * 4);
    unsigned* chunkOff = (unsigned*)alloc((size_t)NCH * 4);
    unsigned* posOf    = (unsigned*)alloc((size_t)EE * 4);
    unsigned* src_s    = (unsigned*)alloc((size_t)EE * 4);
    float2*   ae1s     = (float2*)alloc((size_t)EE * 8);
    float2*   ae2s     = (float2*)alloc((size_t)EE * 8);
    float2*   asrcv    = (float2*)alloc((size_t)NN * 8);
    float2*   adstv    = (float2*)alloc((size_t)NN * 8);
    float2*   hp       = (float2*)alloc((size_t)NN * 64 * 8);
    float*    mid      = (float*)alloc((size_t)NN * 64 * 4);
    float*    rn1      = (float*)alloc((size_t)NN * 4);
    float*    rn2      = (float*)alloc((size_t)NN * 4);
    float*    Wq1      = (float*)alloc(8192 * 4);
    float*    Wq2      = (float*)alloc(8192 * 4);
    float*    v1       = (float*)alloc(64 * 4);
    float*    v2       = (float*)alloc(64 * 4);
    unsigned* slots1   = (unsigned*)alloc(256 * 4);
    unsigned* slots2   = (unsigned*)alloc(256 * 4);
    float*    s1       = (float*)alloc(4);
    float*    s2       = (float*)alloc(4);

    dim3 B(256);
    k_init<<<391, B, 0, stream>>>(deg_src, deg_dst, slots1, slots2);
    k_deg<<<3125, B, 0, stream>>>(ei, deg_src, deg_dst);
    k_scan_chunksum<<<NCH, B, 0, stream>>>(deg_dst, chunkSum);
    k_scan_chunkoff<<<1, B, 0, stream>>>(chunkSum, chunkOff, offs);
    k_scan_final<<<NCH, B, 0, stream>>>(deg_dst, chunkOff, offs, cursor,
                                        deg_src, a1, a2, rn1, rn2);
    k_scatter<<<3125, B, 0, stream>>>(ei, cursor, posOf, src_s);
    k_weights<<<2, B, 0, stream>>>(W1, W2, We1, ae1, We2, ae2, Wq1, Wq2, v1, v2);
    k_aedge<<<3125, B, 0, stream>>>(eattr, v1, v2, posOf, ae1s, ae2s);
    // layer 1
    k_hproj<<<3125, B, 0, stream>>>(x, rn1, Wq1, as1, ad1, hp, asrcv, adstv);
    k_aggregate<<<25000, B, 0, stream>>>(offs, src_s, ae1s, asrcv, adstv, hp, b1, mid, slots1);
    k_amax_reduce<<<1, B, 0, stream>>>(slots1, s1);
    k_quant_relu_norm<<<25000, B, 0, stream>>>(mid, s1, rn2);
    // layer 2
    k_hproj<<<3125, B, 0, stream>>>(mid, nullptr, Wq2, as2, ad2, hp, asrcv, adstv);
    k_aggregate<<<25000, B, 0, stream>>>(offs, src_s, ae2s, asrcv, adstv, hp, b2, out, slots2);
    k_amax_reduce<<<1, B, 0, stream>>>(slots2, s2);
    k_quant_out<<<25000, B, 0, stream>>>(out, s2);
}

// Round 4
// 861.748 us; speedup vs baseline: 1.2641x; 1.2641x over previous
//
#include <hip/hip_runtime.h>
#include <hip/hip_bf16.h>
#include <math.h>

#define NN 100000
#define EE 800000

static constexpr int SCAN_CH = 512;
static constexpr int NCH = (NN + SCAN_CH - 1) / SCAN_CH; // 196

__device__ __forceinline__ float leaky(float a) { return a >= 0.0f ? a : 0.2f * a; }
__device__ __forceinline__ float quantize(float v, float s) {
    float r = rintf(v / s);
    r = fminf(fmaxf(r, -128.0f), 127.0f);
    return r * s;
}

// ---------------- init: zero counters ----------------
__global__ void k_init(unsigned* deg_src, unsigned* deg_dst, unsigned* s1, unsigned* s2) {
    int i = blockIdx.x * 256 + threadIdx.x;
    if (i < NN) { deg_src[i] = 0; deg_dst[i] = 0; }
    if (i < 256) { s1[i] = 0; s2[i] = 0; }
}

// ---------------- degree count ----------------
__global__ void k_deg(const int* ei, unsigned* deg_src, unsigned* deg_dst) {
    int e = blockIdx.x * 256 + threadIdx.x;
    if (e < EE) {
        atomicAdd(&deg_src[ei[e]], 1u);
        atomicAdd(&deg_dst[ei[EE + e]], 1u);
    }
}

// ---------------- scan (3 kernels) ----------------
__global__ void k_scan_chunksum(const unsigned* deg_dst, unsigned* chunkSum) {
    __shared__ unsigned red[256];
    int b = blockIdx.x, t = threadIdx.x;
    int g0 = b * SCAN_CH + t;
    unsigned v = 0;
    if (g0 < NN) v += deg_dst[g0];
    if (g0 + 256 < NN && t + 256 < SCAN_CH) v += deg_dst[g0 + 256];
    red[t] = v; __syncthreads();
    for (int s = 128; s > 0; s >>= 1) { if (t < s) red[t] += red[t + s]; __syncthreads(); }
    if (t == 0) chunkSum[b] = red[0];
}

__global__ void k_scan_chunkoff(const unsigned* chunkSum, unsigned* chunkOff, unsigned* off) {
    __shared__ unsigned sc[256];
    int t = threadIdx.x;
    unsigned v = (t < NCH) ? chunkSum[t] : 0u;
    sc[t] = v; __syncthreads();
    for (int d = 1; d < 256; d <<= 1) {
        unsigned add = (t >= d) ? sc[t - d] : 0u; __syncthreads();
        sc[t] += add; __syncthreads();
    }
    if (t < NCH) chunkOff[t] = sc[t] - v;
    if (t == 255) off[NN] = sc[255];
}

// final scan + cursor init + degree-norm tables (fused)
__global__ void k_scan_final(const unsigned* deg_dst, const unsigned* chunkOff,
                             unsigned* off, unsigned* cursor,
                             const unsigned* deg_src, const float* a1p, const float* a2p,
                             float* rn1, float* rn2) {
    __shared__ unsigned sc[256];
    int b = blockIdx.x, t = threadIdx.x;
    int g0 = b * SCAN_CH + 2 * t;
    unsigned a = (g0 < NN) ? deg_dst[g0] : 0u;
    unsigned c = (g0 + 1 < NN) ? deg_dst[g0 + 1] : 0u;
    unsigned ps = a + c;
    sc[t] = ps; __syncthreads();
    for (int d = 1; d < 256; d <<= 1) {
        unsigned add = (t >= d) ? sc[t - d] : 0u; __syncthreads();
        sc[t] += add; __syncthreads();
    }
    unsigned base = chunkOff[b] + sc[t] - ps;
    float e1 = -a1p[0], e2 = -a2p[0];
    if (g0 < NN) {
        off[g0] = base; cursor[g0] = base;
        float d0 = (float)deg_src[g0] + 1.0f;
        rn1[g0] = powf(d0, e1); rn2[g0] = powf(d0, e2);
    }
    if (g0 + 1 < NN) {
        off[g0 + 1] = base + a; cursor[g0 + 1] = base + a;
        float d1 = (float)deg_src[g0 + 1] + 1.0f;
        rn1[g0 + 1] = powf(d1, e1); rn2[g0 + 1] = powf(d1, e2);
    }
}

// ---------------- scatter: sort edges by dst ----------------
__global__ void k_scatter(const int* ei, unsigned* cursor, unsigned* pos_of_edge,
                          unsigned* src_sorted) {
    int e = blockIdx.x * 256 + threadIdx.x;
    if (e < EE) {
        int d = ei[EE + e];
        unsigned pos = atomicAdd(&cursor[d], 1u);
        pos_of_edge[e] = pos;
        src_sorted[pos] = (unsigned)ei[e];
    }
}

// ---------------- weight fake-quant + a_edge projection vectors ----------------
// block 0: layer 1, block 1: layer 2
__global__ void k_weights(const float* W1, const float* W2,
                          const float* We1, const float* ae1,
                          const float* We2, const float* ae2,
                          float* Wq1, float* Wq2, float* v1, float* v2) {
    __shared__ float red[256];
    int t = threadIdx.x;
    const float* W  = blockIdx.x ? W2 : W1;
    const float* We = blockIdx.x ? We2 : We1;
    const float* ae = blockIdx.x ? ae2 : ae1;
    float* Wq = blockIdx.x ? Wq2 : Wq1;
    float* v  = blockIdx.x ? v2 : v1;
    float m = 0.0f;
    for (int i = t; i < 8192; i += 256) m = fmaxf(m, fabsf(W[i]));
    red[t] = m; __syncthreads();
    for (int s = 128; s > 0; s >>= 1) { if (t < s) red[t] = fmaxf(red[t], red[t + s]); __syncthreads(); }
    float s1 = fmaxf(red[0], 1e-8f) / 127.0f;
    __syncthreads();
    for (int i = t; i < 8192; i += 256) Wq[i] = quantize(W[i], s1);
    if (t < 64) {
        int h = t >> 5, d = t & 31;
        float acc = 0.0f;
        for (int c = 0; c < 64; ++c) acc += We[(h * 64 + c) * 32 + d] * ae[h * 64 + c];
        v[t] = acc;
    }
}

// ---------------- a_edge for both layers, written in dst-sorted order ----------------
__global__ void k_aedge(const float* edge_attr, const float* v1, const float* v2,
                        const unsigned* pos_of_edge, float2* ae1s, float2* ae2s) {
    __shared__ float vs[128];
    int t = threadIdx.x;
    if (t < 64) vs[t] = v1[t];
    else if (t < 128) vs[t] = v2[t - 64];
    __syncthreads();
    int e = blockIdx.x * 256 + t;
    if (e >= EE) return;
    const float4* ea = (const float4*)(edge_attr + (size_t)e * 32);
    float a00 = 0, a01 = 0, a10 = 0, a11 = 0;
#pragma unroll
    for (int q = 0; q < 8; ++q) {
        float4 w = ea[q];
        float xs4[4] = {w.x, w.y, w.z, w.w};
#pragma unroll
        for (int j = 0; j < 4; ++j) {
            int d = q * 4 + j;
            a00 += xs4[j] * vs[d];
            a01 += xs4[j] * vs[32 + d];
            a10 += xs4[j] * vs[64 + d];
            a11 += xs4[j] * vs[96 + d];
        }
    }
    unsigned pos = pos_of_edge[e];
    ae1s[pos] = make_float2(a00, a01);
    ae2s[pos] = make_float2(a10, a11);
}

// ---------------- h = xn @ Wq.T (+ a_src/a_dst dots) ----------------
// Each lane computes BOTH heads for feature l (weight rows l and 64+l in VGPRs:
// 128 VGPRs of weights -> __launch_bounds__(256,2) gives a 256-VGPR budget, no spill).
__global__ void __launch_bounds__(256, 2)
k_hproj(const float* __restrict__ in, const float* __restrict__ rn,
        const float* __restrict__ Wq,
        const float* __restrict__ att_s, const float* __restrict__ att_d,
        float2* __restrict__ hp, float2* __restrict__ asrcv,
        float2* __restrict__ adstv) {
    __shared__ float xs[32][64];   // 8 KB
    int t = threadIdx.x;
    int node0 = blockIdx.x * 32;
    for (int i = t; i < 512; i += 256) {
        int n = i >> 4, c4 = i & 15;
        int node = node0 + n;
        float4 v = make_float4(0.f, 0.f, 0.f, 0.f);
        if (node < NN) {
            v = ((const float4*)(in + (size_t)node * 64))[c4];
            if (rn) { float r = rn[node]; v.x *= r; v.y *= r; v.z *= r; v.w *= r; }
        }
        ((float4*)xs[n])[c4] = v;
    }
    int w = t >> 6, l = t & 63;
    float4 w0[16], w1[16];
    const float4* wp0 = (const float4*)(Wq + (size_t)l * 64);
    const float4* wp1 = (const float4*)(Wq + (size_t)(64 + l) * 64);
#pragma unroll
    for (int q = 0; q < 16; ++q) { w0[q] = wp0[q]; w1[q] = wp1[q]; }
    float as0 = att_s[l], as1 = att_s[64 + l];
    float ad0 = att_d[l], ad1 = att_d[64 + l];
    __syncthreads();
    for (int nn = 0; nn < 8; ++nn) {
        int node = node0 + w * 8 + nn;
        if (node >= NN) break;
        const float4* xr = (const float4*)xs[w * 8 + nn];
        float a0 = 0.0f, a1 = 0.0f;
#pragma unroll
        for (int q = 0; q < 16; ++q) {
            float4 xv = xr[q];             // uniform address -> LDS broadcast
            a0 += xv.x * w0[q].x + xv.y * w0[q].y + xv.z * w0[q].z + xv.w * w0[q].w;
            a1 += xv.x * w1[q].x + xv.y * w1[q].y + xv.z * w1[q].z + xv.w * w1[q].w;
        }
        hp[(size_t)node * 64 + l] = make_float2(a0, a1);
        float ps0 = a0 * as0, ps1 = a1 * as1, pd0 = a0 * ad0, pd1 = a1 * ad1;
#pragma unroll
        for (int m = 32; m > 0; m >>= 1) {
            ps0 += __shfl_xor(ps0, m, 64);
            ps1 += __shfl_xor(ps1, m, 64);
            pd0 += __shfl_xor(pd0, m, 64);
            pd1 += __shfl_xor(pd1, m, 64);
        }
        if (l == 0) {
            asrcv[node] = make_float2(ps0, ps1);
            adstv[node] = make_float2(pd0, pd1);
        }
    }
}

// ---------------- fused softmax+aggregate: wave per dst node, 4-way unrolled ----------------
__global__ void k_aggregate(const unsigned* __restrict__ off, const unsigned* __restrict__ src_s,
                            const float2* __restrict__ aes,
                            const float2* __restrict__ asrcv, const float2* __restrict__ adstv,
                            const float2* __restrict__ hp, const float* __restrict__ bias,
                            float* __restrict__ outp, unsigned* __restrict__ amax_slots) {
    int t = threadIdx.x;
    int l = t & 63;
    int node = blockIdx.x * 4 + (t >> 6);
    if (node >= NN) return;
    unsigned s0 = off[node], e0 = off[node + 1];
    float2 adv = adstv[node];
    float acc0 = 0.f, acc1 = 0.f, sum0 = 0.f, sum1 = 0.f;
    unsigned i = s0;
    for (; i + 4 <= e0; i += 4) {
        unsigned sa = src_s[i], sb = src_s[i + 1], sc = src_s[i + 2], sd = src_s[i + 3];
        float2 ea = aes[i], eb = aes[i + 1], ec = aes[i + 2], ed = aes[i + 3];
        float2 aa = asrcv[sa], ab = asrcv[sb], ac = asrcv[sc], ad = asrcv[sd];
        float2 ha = hp[(size_t)sa * 64 + l];
        float2 hb = hp[(size_t)sb * 64 + l];
        float2 hc = hp[(size_t)sc * 64 + l];
        float2 hd = hp[(size_t)sd * 64 + l];
        float pa0 = __expf(leaky(aa.x + adv.x + ea.x));
        float pa1 = __expf(leaky(aa.y + adv.y + ea.y));
        float pb0 = __expf(leaky(ab.x + adv.x + eb.x));
        float pb1 = __expf(leaky(ab.y + adv.y + eb.y));
        float pc0 = __expf(leaky(ac.x + adv.x + ec.x));
        float pc1 = __expf(leaky(ac.y + adv.y + ec.y));
        float pd0 = __expf(leaky(ad.x + adv.x + ed.x));
        float pd1 = __expf(leaky(ad.y + adv.y + ed.y));
        sum0 += pa0 + pb0 + pc0 + pd0;
        sum1 += pa1 + pb1 + pc1 + pd1;
        acc0 = fmaf(pa0, ha.x, fmaf(pb0, hb.x, fmaf(pc0, hc.x, fmaf(pd0, hd.x, acc0))));
        acc1 = fmaf(pa1, ha.y, fmaf(pb1, hb.y, fmaf(pc1, hc.y, fmaf(pd1, hd.y, acc1))));
    }
    for (; i < e0; ++i) {
        unsigned s = src_s[i];
        float2 ev = aes[i];
        float2 av = asrcv[s];
        float2 hv = hp[(size_t)s * 64 + l];
        float p0 = __expf(leaky(av.x + adv.x + ev.x));
        float p1 = __expf(leaky(av.y + adv.y + ev.y));
        sum0 += p0; sum1 += p1;
        acc0 = fmaf(p0, hv.x, acc0);
        acc1 = fmaf(p1, hv.y, acc1);
    }
    float o = 0.5f * (acc0 / (sum0 + 1e-16f) + acc1 / (sum1 + 1e-16f)) + bias[l];
    outp[(size_t)node * 64 + l] = o;
    float v = fabsf(o);
#pragma unroll
    for (int m = 32; m > 0; m >>= 1) v = fmaxf(v, __shfl_xor(v, m, 64));
    if (l == 0) atomicMax(&amax_slots[node & 255], __float_as_uint(v));
}

// ---------------- reduce 256 absmax slots -> scale ----------------
__global__ void k_amax_reduce(const unsigned* slots, float* s_out) {
    __shared__ unsigned red[256];
    int t = threadIdx.x;
    red[t] = slots[t]; __syncthreads();
    for (int s = 128; s > 0; s >>= 1) {
        if (t < s) red[t] = (red[t] > red[t + s]) ? red[t] : red[t + s];
        __syncthreads();
    }
    if (t == 0) s_out[0] = fmaxf(__uint_as_float(red[0]), 1e-8f) / 127.0f;
}

// ---------------- quant + relu + degree-norm (layer1 -> layer2 input) ----------------
__global__ void k_quant_relu_norm(float* buf, const float* s_in, const float* rn2) {
    int i = blockIdx.x * 256 + threadIdx.x;
    if (i >= NN * 64) return;
    float s = s_in[0];
    float q = quantize(buf[i], s);
    buf[i] = fmaxf(q, 0.0f) * rn2[i >> 6];
}

// ---------------- final output fake-quant in place ----------------
__global__ void k_quant_out(float* buf, const float* s_in) {
    int i = blockIdx.x * 256 + threadIdx.x;
    if (i >= NN * 64) return;
    buf[i] = quantize(buf[i], s_in[0]);
}

extern "C" void kernel_launch(void* const* d_in, const int* in_sizes, int n_in,
                              void* d_out, int out_size, void* d_ws, size_t ws_size,
                              hipStream_t stream) {
    const float* x     = (const float*)d_in[0];
    const int*   ei    = (const int*)d_in[1];
    const float* eattr = (const float*)d_in[2];
    const float* a1    = (const float*)d_in[3];
    const float* W1    = (const float*)d_in[4];
    const float* We1   = (const float*)d_in[5];
    const float* as1   = (const float*)d_in[6];
    const float* ad1   = (const float*)d_in[7];
    const float* ae1   = (const float*)d_in[8];
    const float* b1    = (const float*)d_in[9];
    const float* a2    = (const float*)d_in[10];
    const float* W2    = (const float*)d_in[11];
    const float* We2   = (const float*)d_in[12];
    const float* as2   = (const float*)d_in[13];
    const float* ad2   = (const float*)d_in[14];
    const float* ae2   = (const float*)d_in[15];
    const float* b2    = (const float*)d_in[16];
    float* out = (float*)d_out;

    char* w = (char*)d_ws;
    size_t o = 0;
    auto alloc = [&](size_t bytes) -> char* {
        char* p = w + o;
        o += (bytes + 255) & ~(size_t)255;
        return p;
    };
    unsigned* deg_src  = (unsigned*)alloc((size_t)NN * 4);
    unsigned* deg_dst  = (unsigned*)alloc((size_t)NN * 4);
    unsigned* offs     = (unsigned*)alloc((size_t)(NN + 1) * 4);
    unsigned* cursor   = (unsigned*)alloc((size_t)NN * 4);
    unsigned* chunkSum = (unsigned*)alloc((size_t)NCH * 4);
    unsigned* chunkOff = (unsigned*)alloc((size_t)NCH * 4);
    unsigned* posOf    = (unsigned*)alloc((size_t)EE * 4);
    unsigned* src_s    = (unsigned*)alloc((size_t)EE * 4);
    float2*   ae1s     = (float2*)alloc((size_t)EE * 8);
    float2*   ae2s     = (float2*)alloc((size_t)EE * 8);
    float2*   asrcv    = (float2*)alloc((size_t)NN * 8);
    float2*   adstv    = (float2*)alloc((size_t)NN * 8);
    float2*   hp       = (float2*)alloc((size_t)NN * 64 * 8);
    float*    mid      = (float*)alloc((size_t)NN * 64 * 4);
    float*    rn1      = (float*)alloc((size_t)NN * 4);
    float*    rn2      = (float*)alloc((size_t)NN * 4);
    float*    Wq1      = (float*)alloc(8192 * 4);
    float*    Wq2      = (float*)alloc(8192 * 4);
    float*    v1       = (float*)alloc(64 * 4);
    float*    v2       = (float*)alloc(64 * 4);
    unsigned* slots1   = (unsigned*)alloc(256 * 4);
    unsigned* slots2   = (unsigned*)alloc(256 * 4);
    float*    s1       = (float*)alloc(4);
    float*    s2       = (float*)alloc(4);

    dim3 B(256);
    k_init<<<391, B, 0, stream>>>(deg_src, deg_dst, slots1, slots2);
    k_deg<<<3125, B, 0, stream>>>(ei, deg_src, deg_dst);
    k_scan_chunksum<<<NCH, B, 0, stream>>>(deg_dst, chunkSum);
    k_scan_chunkoff<<<1, B, 0, stream>>>(chunkSum, chunkOff, offs);
    k_scan_final<<<NCH, B, 0, stream>>>(deg_dst, chunkOff, offs, cursor,
                                        deg_src, a1, a2, rn1, rn2);
    k_scatter<<<3125, B, 0, stream>>>(ei, cursor, posOf, src_s);
    k_weights<<<2, B, 0, stream>>>(W1, W2, We1, ae1, We2, ae2, Wq1, Wq2, v1, v2);
    k_aedge<<<3125, B, 0, stream>>>(eattr, v1, v2, posOf, ae1s, ae2s);
    // layer 1
    k_hproj<<<3125, B, 0, stream>>>(x, rn1, Wq1, as1, ad1, hp, asrcv, adstv);
    k_aggregate<<<25000, B, 0, stream>>>(offs, src_s, ae1s, asrcv, adstv, hp, b1, mid, slots1);
    k_amax_reduce<<<1, B, 0, stream>>>(slots1, s1);
    k_quant_relu_norm<<<25000, B, 0, stream>>>(mid, s1, rn2);
    // layer 2
    k_hproj<<<3125, B, 0, stream>>>(mid, nullptr, Wq2, as2, ad2, hp, asrcv, adstv);
    k_aggregate<<<25000, B, 0, stream>>>(offs, src_s, ae2s, asrcv, adstv, hp, b2, out, slots2);
    k_amax_reduce<<<1, B, 0, stream>>>(slots2, s2);
    k_quant_out<<<25000, B, 0, stream>>>(out, s2);
}

// Round 5
// 817.390 us; speedup vs baseline: 1.3327x; 1.0543x over previous
//
#include <hip/hip_runtime.h>
#include <hip/hip_bf16.h>
#include <math.h>

#define NN 100000
#define EE 800000

static constexpr int SCAN_CH = 512;
static constexpr int NCH = (NN + SCAN_CH - 1) / SCAN_CH; // 196

__device__ __forceinline__ float leaky(float a) { return a >= 0.0f ? a : 0.2f * a; }
__device__ __forceinline__ float quantize(float v, float s) {
    float r = rintf(v / s);
    r = fminf(fmaxf(r, -128.0f), 127.0f);
    return r * s;
}

// ---------------- init: zero counters ----------------
__global__ void k_init(unsigned* deg_src, unsigned* deg_dst, unsigned* s1, unsigned* s2) {
    int i = blockIdx.x * 256 + threadIdx.x;
    if (i < NN) { deg_src[i] = 0; deg_dst[i] = 0; }
    if (i < 256) { s1[i] = 0; s2[i] = 0; }
}

// ---------------- degree count ----------------
__global__ void k_deg(const int* ei, unsigned* deg_src, unsigned* deg_dst) {
    int e = blockIdx.x * 256 + threadIdx.x;
    if (e < EE) {
        atomicAdd(&deg_src[ei[e]], 1u);
        atomicAdd(&deg_dst[ei[EE + e]], 1u);
    }
}

// ---------------- scan (3 kernels) ----------------
__global__ void k_scan_chunksum(const unsigned* deg_dst, unsigned* chunkSum) {
    __shared__ unsigned red[256];
    int b = blockIdx.x, t = threadIdx.x;
    int g0 = b * SCAN_CH + t;
    unsigned v = 0;
    if (g0 < NN) v += deg_dst[g0];
    if (g0 + 256 < NN && t + 256 < SCAN_CH) v += deg_dst[g0 + 256];
    red[t] = v; __syncthreads();
    for (int s = 128; s > 0; s >>= 1) { if (t < s) red[t] += red[t + s]; __syncthreads(); }
    if (t == 0) chunkSum[b] = red[0];
}

__global__ void k_scan_chunkoff(const unsigned* chunkSum, unsigned* chunkOff, unsigned* off) {
    __shared__ unsigned sc[256];
    int t = threadIdx.x;
    unsigned v = (t < NCH) ? chunkSum[t] : 0u;
    sc[t] = v; __syncthreads();
    for (int d = 1; d < 256; d <<= 1) {
        unsigned add = (t >= d) ? sc[t - d] : 0u; __syncthreads();
        sc[t] += add; __syncthreads();
    }
    if (t < NCH) chunkOff[t] = sc[t] - v;
    if (t == 255) off[NN] = sc[255];
}

// final scan + cursor init + degree-norm tables (fused)
__global__ void k_scan_final(const unsigned* deg_dst, const unsigned* chunkOff,
                             unsigned* off, unsigned* cursor,
                             const unsigned* deg_src, const float* a1p, const float* a2p,
                             float* rn1, float* rn2) {
    __shared__ unsigned sc[256];
    int b = blockIdx.x, t = threadIdx.x;
    int g0 = b * SCAN_CH + 2 * t;
    unsigned a = (g0 < NN) ? deg_dst[g0] : 0u;
    unsigned c = (g0 + 1 < NN) ? deg_dst[g0 + 1] : 0u;
    unsigned ps = a + c;
    sc[t] = ps; __syncthreads();
    for (int d = 1; d < 256; d <<= 1) {
        unsigned add = (t >= d) ? sc[t - d] : 0u; __syncthreads();
        sc[t] += add; __syncthreads();
    }
    unsigned base = chunkOff[b] + sc[t] - ps;
    float e1 = -a1p[0], e2 = -a2p[0];
    if (g0 < NN) {
        off[g0] = base; cursor[g0] = base;
        float d0 = (float)deg_src[g0] + 1.0f;
        rn1[g0] = powf(d0, e1); rn2[g0] = powf(d0, e2);
    }
    if (g0 + 1 < NN) {
        off[g0 + 1] = base + a; cursor[g0 + 1] = base + a;
        float d1 = (float)deg_src[g0 + 1] + 1.0f;
        rn1[g0 + 1] = powf(d1, e1); rn2[g0 + 1] = powf(d1, e2);
    }
}

// ---------------- scatter: sort edges by dst ----------------
__global__ void k_scatter(const int* ei, unsigned* cursor, unsigned* perm,
                          unsigned* src_sorted) {
    int e = blockIdx.x * 256 + threadIdx.x;
    if (e < EE) {
        int d = ei[EE + e];
        unsigned pos = atomicAdd(&cursor[d], 1u);
        perm[pos] = (unsigned)e;
        src_sorted[pos] = (unsigned)ei[e];
    }
}

// ---------------- weight fake-quant + a_edge projection vectors ----------------
// block 0: layer 1, block 1: layer 2
__global__ void k_weights(const float* W1, const float* W2,
                          const float* We1, const float* ae1,
                          const float* We2, const float* ae2,
                          float* Wq1, float* Wq2, float* v1, float* v2) {
    __shared__ float red[256];
    int t = threadIdx.x;
    const float* W  = blockIdx.x ? W2 : W1;
    const float* We = blockIdx.x ? We2 : We1;
    const float* ae = blockIdx.x ? ae2 : ae1;
    float* Wq = blockIdx.x ? Wq2 : Wq1;
    float* v  = blockIdx.x ? v2 : v1;
    float m = 0.0f;
    for (int i = t; i < 8192; i += 256) m = fmaxf(m, fabsf(W[i]));
    red[t] = m; __syncthreads();
    for (int s = 128; s > 0; s >>= 1) { if (t < s) red[t] = fmaxf(red[t], red[t + s]); __syncthreads(); }
    float s1 = fmaxf(red[0], 1e-8f) / 127.0f;
    __syncthreads();
    for (int i = t; i < 8192; i += 256) Wq[i] = quantize(W[i], s1);
    if (t < 64) {
        int h = t >> 5, d = t & 31;
        float acc = 0.0f;
        for (int c = 0; c < 64; ++c) acc += We[(h * 64 + c) * 32 + d] * ae[h * 64 + c];
        v[t] = acc;
    }
}

// ---------------- a_edge for both layers, edge order (fully coalesced) ----------------
__global__ void k_aedge(const float* edge_attr, const float* v1, const float* v2,
                        float2* ae1e, float2* ae2e) {
    __shared__ float vs[128];
    int t = threadIdx.x;
    if (t < 64) vs[t] = v1[t];
    else if (t < 128) vs[t] = v2[t - 64];
    __syncthreads();
    int e = blockIdx.x * 256 + t;
    if (e >= EE) return;
    const float4* ea = (const float4*)(edge_attr + (size_t)e * 32);
    float a00 = 0, a01 = 0, a10 = 0, a11 = 0;
#pragma unroll
    for (int q = 0; q < 8; ++q) {
        float4 w = ea[q];
        float xs4[4] = {w.x, w.y, w.z, w.w};
#pragma unroll
        for (int j = 0; j < 4; ++j) {
            int d = q * 4 + j;
            a00 += xs4[j] * vs[d];
            a01 += xs4[j] * vs[32 + d];
            a10 += xs4[j] * vs[64 + d];
            a11 += xs4[j] * vs[96 + d];
        }
    }
    ae1e[e] = make_float2(a00, a01);
    ae2e[e] = make_float2(a10, a11);
}

// ---------------- h = xn @ Wq.T (+ a_src/a_dst dots) ----------------
// Each lane computes BOTH heads for feature l (weight rows l and 64+l in VGPRs:
// 128 VGPRs of weights -> __launch_bounds__(256,2) gives a 256-VGPR budget, no spill).
__global__ void __launch_bounds__(256, 2)
k_hproj(const float* __restrict__ in, const float* __restrict__ rn,
        const float* __restrict__ Wq,
        const float* __restrict__ att_s, const float* __restrict__ att_d,
        float2* __restrict__ hp, float2* __restrict__ asrcv,
        float2* __restrict__ adstv) {
    __shared__ float xs[32][64];   // 8 KB
    int t = threadIdx.x;
    int node0 = blockIdx.x * 32;
    for (int i = t; i < 512; i += 256) {
        int n = i >> 4, c4 = i & 15;
        int node = node0 + n;
        float4 v = make_float4(0.f, 0.f, 0.f, 0.f);
        if (node < NN) {
            v = ((const float4*)(in + (size_t)node * 64))[c4];
            if (rn) { float r = rn[node]; v.x *= r; v.y *= r; v.z *= r; v.w *= r; }
        }
        ((float4*)xs[n])[c4] = v;
    }
    int w = t >> 6, l = t & 63;
    float4 w0[16], w1[16];
    const float4* wp0 = (const float4*)(Wq + (size_t)l * 64);
    const float4* wp1 = (const float4*)(Wq + (size_t)(64 + l) * 64);
#pragma unroll
    for (int q = 0; q < 16; ++q) { w0[q] = wp0[q]; w1[q] = wp1[q]; }
    float as0 = att_s[l], as1 = att_s[64 + l];
    float ad0 = att_d[l], ad1 = att_d[64 + l];
    __syncthreads();
    for (int nn = 0; nn < 8; ++nn) {
        int node = node0 + w * 8 + nn;
        if (node >= NN) break;
        const float4* xr = (const float4*)xs[w * 8 + nn];
        float a0 = 0.0f, a1 = 0.0f;
#pragma unroll
        for (int q = 0; q < 16; ++q) {
            float4 xv = xr[q];             // uniform address -> LDS broadcast
            a0 += xv.x * w0[q].x + xv.y * w0[q].y + xv.z * w0[q].z + xv.w * w0[q].w;
            a1 += xv.x * w1[q].x + xv.y * w1[q].y + xv.z * w1[q].z + xv.w * w1[q].w;
        }
        hp[(size_t)node * 64 + l] = make_float2(a0, a1);
        float ps0 = a0 * as0, ps1 = a1 * as1, pd0 = a0 * ad0, pd1 = a1 * ad1;
#pragma unroll
        for (int m = 32; m > 0; m >>= 1) {
            ps0 += __shfl_xor(ps0, m, 64);
            ps1 += __shfl_xor(ps1, m, 64);
            pd0 += __shfl_xor(pd0, m, 64);
            pd1 += __shfl_xor(pd1, m, 64);
        }
        if (l == 0) {
            asrcv[node] = make_float2(ps0, ps1);
            adstv[node] = make_float2(pd0, pd1);
        }
    }
}

// ---------------- fused softmax+aggregate: wave per dst node ----------------
// Phase 1 (lane-parallel): lanes l<deg load edge metadata & compute p = exp(leaky(.))
// Phase 2 (broadcast): readlane (src, p0, p1) from lane j; 4 independent hp gathers/group.
__global__ void k_aggregate(const unsigned* __restrict__ off, const unsigned* __restrict__ src_s,
                            const unsigned* __restrict__ perm,
                            const float2* __restrict__ aee,
                            const float2* __restrict__ asrcv, const float2* __restrict__ adstv,
                            const float2* __restrict__ hp, const float* __restrict__ bias,
                            float* __restrict__ outp, unsigned* __restrict__ amax_slots) {
    int t = threadIdx.x;
    int l = t & 63;
    int node = blockIdx.x * 4 + (t >> 6);
    if (node >= NN) return;
    unsigned s0 = off[node], e0 = off[node + 1];
    float2 adv = adstv[node];
    float acc0 = 0.f, acc1 = 0.f, psum0 = 0.f, psum1 = 0.f;
    for (unsigned base = s0; base < e0; base += 64) {
        int cnt = (int)min(64u, e0 - base);
        float p0 = 0.f, p1 = 0.f;
        unsigned s = 0u;
        if (l < cnt) {
            s = src_s[base + l];                 // coalesced
            unsigned pe = perm[base + l];        // coalesced
            float2 ev = aee[pe];                 // parallel 8B gather (L3)
            float2 av = asrcv[s];                // parallel 8B gather (L2/L3)
            p0 = __expf(leaky(av.x + adv.x + ev.x));
            p1 = __expf(leaky(av.y + adv.y + ev.y));
        }
        psum0 += p0; psum1 += p1;
        int su = (int)s;
        unsigned pu0 = __float_as_uint(p0), pu1 = __float_as_uint(p1);
        for (int j = 0; j < cnt; j += 4) {
            unsigned sa = (unsigned)__builtin_amdgcn_readlane(su, j);
            unsigned sb = (unsigned)__builtin_amdgcn_readlane(su, j + 1);
            unsigned sc = (unsigned)__builtin_amdgcn_readlane(su, j + 2);
            unsigned sd = (unsigned)__builtin_amdgcn_readlane(su, j + 3);
            float2 ha = hp[(size_t)sa * 64 + l];
            float2 hb = hp[(size_t)sb * 64 + l];
            float2 hc = hp[(size_t)sc * 64 + l];
            float2 hd = hp[(size_t)sd * 64 + l];
            float qa0 = __uint_as_float((unsigned)__builtin_amdgcn_readlane((int)pu0, j));
            float qa1 = __uint_as_float((unsigned)__builtin_amdgcn_readlane((int)pu1, j));
            float qb0 = __uint_as_float((unsigned)__builtin_amdgcn_readlane((int)pu0, j + 1));
            float qb1 = __uint_as_float((unsigned)__builtin_amdgcn_readlane((int)pu1, j + 1));
            float qc0 = __uint_as_float((unsigned)__builtin_amdgcn_readlane((int)pu0, j + 2));
            float qc1 = __uint_as_float((unsigned)__builtin_amdgcn_readlane((int)pu1, j + 2));
            float qd0 = __uint_as_float((unsigned)__builtin_amdgcn_readlane((int)pu0, j + 3));
            float qd1 = __uint_as_float((unsigned)__builtin_amdgcn_readlane((int)pu1, j + 3));
            acc0 = fmaf(qa0, ha.x, fmaf(qb0, hb.x, fmaf(qc0, hc.x, fmaf(qd0, hd.x, acc0))));
            acc1 = fmaf(qa1, ha.y, fmaf(qb1, hb.y, fmaf(qc1, hc.y, fmaf(qd1, hd.y, acc1))));
        }
    }
#pragma unroll
    for (int m = 32; m > 0; m >>= 1) {
        psum0 += __shfl_xor(psum0, m, 64);
        psum1 += __shfl_xor(psum1, m, 64);
    }
    float o = 0.5f * (acc0 / (psum0 + 1e-16f) + acc1 / (psum1 + 1e-16f)) + bias[l];
    outp[(size_t)node * 64 + l] = o;
    float v = fabsf(o);
#pragma unroll
    for (int m = 32; m > 0; m >>= 1) v = fmaxf(v, __shfl_xor(v, m, 64));
    if (l == 0) atomicMax(&amax_slots[node & 255], __float_as_uint(v));
}

// ---------------- reduce 256 absmax slots -> scale ----------------
__global__ void k_amax_reduce(const unsigned* slots, float* s_out) {
    __shared__ unsigned red[256];
    int t = threadIdx.x;
    red[t] = slots[t]; __syncthreads();
    for (int s = 128; s > 0; s >>= 1) {
        if (t < s) red[t] = (red[t] > red[t + s]) ? red[t] : red[t + s];
        __syncthreads();
    }
    if (t == 0) s_out[0] = fmaxf(__uint_as_float(red[0]), 1e-8f) / 127.0f;
}

// ---------------- quant + relu + degree-norm (layer1 -> layer2 input) ----------------
__global__ void k_quant_relu_norm(float* buf, const float* s_in, const float* rn2) {
    int i = blockIdx.x * 256 + threadIdx.x;
    if (i >= NN * 64) return;
    float s = s_in[0];
    float q = quantize(buf[i], s);
    buf[i] = fmaxf(q, 0.0f) * rn2[i >> 6];
}

// ---------------- final output fake-quant in place ----------------
__global__ void k_quant_out(float* buf, const float* s_in) {
    int i = blockIdx.x * 256 + threadIdx.x;
    if (i >= NN * 64) return;
    buf[i] = quantize(buf[i], s_in[0]);
}

extern "C" void kernel_launch(void* const* d_in, const int* in_sizes, int n_in,
                              void* d_out, int out_size, void* d_ws, size_t ws_size,
                              hipStream_t stream) {
    const float* x     = (const float*)d_in[0];
    const int*   ei    = (const int*)d_in[1];
    const float* eattr = (const float*)d_in[2];
    const float* a1    = (const float*)d_in[3];
    const float* W1    = (const float*)d_in[4];
    const float* We1   = (const float*)d_in[5];
    const float* as1   = (const float*)d_in[6];
    const float* ad1   = (const float*)d_in[7];
    const float* ae1   = (const float*)d_in[8];
    const float* b1    = (const float*)d_in[9];
    const float* a2    = (const float*)d_in[10];
    const float* W2    = (const float*)d_in[11];
    const float* We2   = (const float*)d_in[12];
    const float* as2   = (const float*)d_in[13];
    const float* ad2   = (const float*)d_in[14];
    const float* ae2   = (const float*)d_in[15];
    const float* b2    = (const float*)d_in[16];
    float* out = (float*)d_out;

    char* w = (char*)d_ws;
    size_t o = 0;
    auto alloc = [&](size_t bytes) -> char* {
        char* p = w + o;
        o += (bytes + 255) & ~(size_t)255;
        return p;
    };
    unsigned* deg_src  = (unsigned*)alloc((size_t)NN * 4);
    unsigned* deg_dst  = (unsigned*)alloc((size_t)NN * 4);
    unsigned* offs     = (unsigned*)alloc((size_t)(NN + 1) * 4);
    unsigned* cursor   = (unsigned*)alloc((size_t)NN * 4);
    unsigned* chunkSum = (unsigned*)alloc((size_t)NCH * 4);
    unsigned* chunkOff = (unsigned*)alloc((size_t)NCH * 4);
    unsigned* perm     = (unsigned*)alloc((size_t)EE * 4);
    unsigned* src_s    = (unsigned*)alloc((size_t)EE * 4);
    float2*   ae1e     = (float2*)alloc((size_t)EE * 8);
    float2*   ae2e     = (float2*)alloc((size_t)EE * 8);
    float2*   asrcv    = (float2*)alloc((size_t)NN * 8);
    float2*   adstv    = (float2*)alloc((size_t)NN * 8);
    float2*   hp       = (float2*)alloc((size_t)NN * 64 * 8);
    float*    mid      = (float*)alloc((size_t)NN * 64 * 4);
    float*    rn1      = (float*)alloc((size_t)NN * 4);
    float*    rn2      = (float*)alloc((size_t)NN * 4);
    float*    Wq1      = (float*)alloc(8192 * 4);
    float*    Wq2      = (float*)alloc(8192 * 4);
    float*    v1       = (float*)alloc(64 * 4);
    float*    v2       = (float*)alloc(64 * 4);
    unsigned* slots1   = (unsigned*)alloc(256 * 4);
    unsigned* slots2   = (unsigned*)alloc(256 * 4);
    float*    s1       = (float*)alloc(4);
    float*    s2       = (float*)alloc(4);

    dim3 B(256);
    k_init<<<391, B, 0, stream>>>(deg_src, deg_dst, slots1, slots2);
    k_deg<<<3125, B, 0, stream>>>(ei, deg_src, deg_dst);
    k_scan_chunksum<<<NCH, B, 0, stream>>>(deg_dst, chunkSum);
    k_scan_chunkoff<<<1, B, 0, stream>>>(chunkSum, chunkOff, offs);
    k_scan_final<<<NCH, B, 0, stream>>>(deg_dst, chunkOff, offs, cursor,
                                        deg_src, a1, a2, rn1, rn2);
    k_scatter<<<3125, B, 0, stream>>>(ei, cursor, perm, src_s);
    k_weights<<<2, B, 0, stream>>>(W1, W2, We1, ae1, We2, ae2, Wq1, Wq2, v1, v2);
    k_aedge<<<3125, B, 0, stream>>>(eattr, v1, v2, ae1e, ae2e);
    // layer 1
    k_hproj<<<3125, B, 0, stream>>>(x, rn1, Wq1, as1, ad1, hp, asrcv, adstv);
    k_aggregate<<<25000, B, 0, stream>>>(offs, src_s, perm, ae1e, asrcv, adstv, hp, b1, mid, slots1);
    k_amax_reduce<<<1, B, 0, stream>>>(slots1, s1);
    k_quant_relu_norm<<<25000, B, 0, stream>>>(mid, s1, rn2);
    // layer 2
    k_hproj<<<3125, B, 0, stream>>>(mid, nullptr, Wq2, as2, ad2, hp, asrcv, adstv);
    k_aggregate<<<25000, B, 0, stream>>>(offs, src_s, perm, ae2e, asrcv, adstv, hp, b2, out, slots2);
    k_amax_reduce<<<1, B, 0, stream>>>(slots2, s2);
    k_quant_out<<<25000, B, 0, stream>>>(out, s2);
}